// Round 2
// baseline (501.286 us; speedup 1.0000x reference)
//
#include <hip/hip_runtime.h>
#include <hip/hip_bf16.h>
#include <stdint.h>

#define IN_F   4096
#define OUT_F  4096
#define BATCH  8192
#define CAP    492

typedef __bf16 v8bf __attribute__((ext_vector_type(8)));
typedef __bf16 v4bf __attribute__((ext_vector_type(4)));
typedef float  v4f  __attribute__((ext_vector_type(4)));

// proper addrspace casts (addrspacecast, NOT integer truncation)
#define GPTR(p) ((const __attribute__((address_space(1))) void*)(p))
#define LPTR(p) ((__attribute__((address_space(3))) void*)(p))

// ---------------------------------------------------------------------------
// convert: X fp32 -> bf16, streaming. 1024 blocks x 256 threads, 32 float4
// per thread, batches of 8 independent loads. UNCHANGED this round.
// ---------------------------------------------------------------------------
__global__ __launch_bounds__(256) void convert_kernel(
    const float4* __restrict__ X4,      // [BATCH*IN_F/4]
    v4bf* __restrict__ Xb4)             // [BATCH*IN_F/4]
{
    const int t = threadIdx.x;
    const size_t base = (size_t)blockIdx.x * 8192 + t;
    #pragma unroll
    for (int u = 0; u < 4; ++u) {
        float4 f[8];
        #pragma unroll
        for (int j = 0; j < 8; ++j)
            f[j] = X4[base + (size_t)(u * 8 + j) * 256];
        #pragma unroll
        for (int j = 0; j < 8; ++j) {
            v4bf o;
            o[0] = (__bf16)f[j].x; o[1] = (__bf16)f[j].y;
            o[2] = (__bf16)f[j].z; o[3] = (__bf16)f[j].w;
            Xb4[base + (size_t)(u * 8 + j) * 256] = o;
        }
    }
}

// ---------------------------------------------------------------------------
// densify: padded CSR -> dense bf16 W[OUT_F x IN_F]. UNCHANGED this round.
// ---------------------------------------------------------------------------
__global__ __launch_bounds__(256) void densify_kernel(
    const float* __restrict__ values,   // [OUT_F, CAP] fp32
    const int* __restrict__ col_idx,    // [OUT_F, CAP]
    __hip_bfloat16* __restrict__ W)     // [OUT_F, IN_F] bf16 out
{
    __shared__ float rowf[2 * IN_F];    // 32 KiB
    const int t = threadIdx.x;

    #pragma unroll
    for (int i = 0; i < (2 * IN_F) / 256; ++i)
        rowf[t + i * 256] = 0.0f;
    __syncthreads();

    const int r    = t >> 7;                  // 0..1 local row
    const int j    = t & 127;                 // 128 threads per row
    const int o    = blockIdx.x * 2 + r;
    const int base = o * CAP;
    for (int k = j; k < CAP; k += 128) {
        float v = values[base + k];           // padding slots are exactly 0
        int   c = col_idx[base + k];
        if (v != 0.0f)
            atomicAdd(&rowf[r * IN_F + c], v); // duplicates must accumulate
    }
    __syncthreads();

    __hip_bfloat162* W2 = reinterpret_cast<__hip_bfloat162*>(W)
                        + (size_t)blockIdx.x * IN_F;
    #pragma unroll
    for (int i = 0; i < IN_F / 256; ++i) {
        int idx = t + i * 256;
        __hip_bfloat162 h2;
        h2.x = __float2bfloat16(rowf[2 * idx]);
        h2.y = __float2bfloat16(rowf[2 * idx + 1]);
        W2[idx] = h2;
    }
}

// ---------------------------------------------------------------------------
// GEMM + bias: Y[b, o] = Xb[b, :] . W[o, :] + bias[o]   (fp32 out)
// 256x256 tile, BK=64, 512 threads = 8 waves (2M x 4N), per-wave 128x64 out
// (acc[8][4] of 16x16 frags). LDS 128 KiB = 2 dbuf x 4 half-regions x 16 KiB
// (A-h0, A-h1, B-h0, B-h1; half = 128 rows x 64 k bf16).
//
// Schedule (T3+T4+T5, race-free by construction):
//   per K-tile kt: 4 phases. Phase p stages half p of kt+1 (2 global_load_lds
//   per thread) into buf^1, then reads 8 swizzled ds_read_b128 frags from buf,
//   setprio(1), 16 MFMA, setprio(0), s_barrier.
//   One counted vmcnt(2) per K-tile at p0, AFTER p0's stage issue: FIFO vmcnt
//   drains exactly kt's 4 halves (8 loads) leaving the just-issued half in
//   flight -> pipeline never drains to 0. Halves are issued 4 phases before
//   first read (~2500 cy > 900 cy HBM latency). p0 barrier after the vmcnt
//   makes all waves' staging visible; the p3 trailing barrier protects buf
//   reuse at distance 2 (H[kt+2,0] issued at kt+1.p0 overwrites buf, last
//   read at kt.p3 before that barrier).
//
// LDS swizzle: slot(r', g) = region*1024 + r'*8 + (g ^ (r'&7)); staging
// pre-swizzles the GLOBAL granule (dest stays linear for global_load_lds);
// frag reads use kg = (ks*4+q) ^ (ml&7). Quarter-wave groups (q fixed) give
// 2-way aliasing only = free (measured 0 conflicts on the 128^2 version).
// ---------------------------------------------------------------------------
__global__ __launch_bounds__(512, 2) void gemm_bias_kernel(
    const __hip_bfloat16* __restrict__ X,     // [BATCH, IN_F] bf16
    const __hip_bfloat16* __restrict__ W,     // [OUT_F, IN_F] bf16
    const float* __restrict__ bias,           // [OUT_F] fp32
    float* __restrict__ Y)                    // [BATCH, OUT_F] fp32
{
    __shared__ uint4 smem[8192];              // 128 KiB, 16B granules

    const int t    = threadIdx.x;             // 0..511
    const int wave = t >> 6;                  // 0..7
    const int lane = t & 63;
    const int ml   = lane & 15;
    const int q    = lane >> 4;
    const int wm   = wave >> 2;               // 0..1  (M)
    const int wn   = wave & 3;                // 0..3  (N)
    const int xr   = ml & 7;

    // XCD-aware swizzle, bn-major per XCD: each XCD owns 2 bn columns so its
    // W panel (2*256 rows = 4 MiB bf16... 512 rows x 4096 x 2B = 4 MiB) stays
    // in its private L2. nwg = 512, 512 % 8 == 0 -> simple swizzle bijective.
    const int flat = blockIdx.y * 16 + blockIdx.x;   // 0..511
    const int u    = (flat & 7) * 64 + (flat >> 3);
    const int bn   = u >> 5;                  // 0..15 (output tiles)
    const int bm   = u & 31;                  // 0..31 (batch tiles)

    // staging source: thread t covers row (t>>3) of a 64-row chunk, granule
    // pre-swizzled so linear LDS dest yields slot(r',g) = g ^ (r'&7).
    const int rbase = t >> 3;                        // 0..63
    const int gsw   = (t & 7) ^ ((t >> 3) & 7);
    const __hip_bfloat16* gA = X + (size_t)(bm * 256 + rbase) * IN_F + gsw * 8;
    const __hip_bfloat16* gB = W + (size_t)(bn * 256 + rbase) * IN_F + gsw * 8;

    // frag read bases (granule units). region(buf,op,h) = buf*4 + op*2 + h.
    const int aRow = wm * 1024 + ml * 8;                           // A half = wm
    const int bRow = (2 + (wn >> 1)) * 1024 + ((wn & 1) * 64 + ml) * 8;

    v4f acc[8][4] = {};

    // prologue: stage all 4 halves of kt=0 into buf 0 (8 loads/thread)
    #pragma unroll
    for (int p = 0; p < 4; ++p) {
        const __hip_bfloat16* src = (p & 1) ? gB : gA;
        const int reg = (p & 1) * 2 + (p >> 1);
        const int hof = (p >> 1) * 128;
        __builtin_amdgcn_global_load_lds(GPTR(src + (size_t)(hof + 0) * IN_F),
            LPTR(&smem[reg * 1024 + 0 + wave * 64]), 16, 0, 0);
        __builtin_amdgcn_global_load_lds(GPTR(src + (size_t)(hof + 64) * IN_F),
            LPTR(&smem[reg * 1024 + 512 + wave * 64]), 16, 0, 0);
    }

    for (int kt = 0; kt < 63; ++kt) {
        const int bufb = kt & 1;
        const __hip_bfloat16* gAk = gA + (kt + 1) * 64;
        const __hip_bfloat16* gBk = gB + (kt + 1) * 64;
        #pragma unroll
        for (int p = 0; p < 4; ++p) {
            // stage half p of kt+1 into buf^1
            {
                const __hip_bfloat16* src = (p & 1) ? gBk : gAk;
                const int reg = (bufb ^ 1) * 4 + (p & 1) * 2 + (p >> 1);
                const int hof = (p >> 1) * 128;
                __builtin_amdgcn_global_load_lds(GPTR(src + (size_t)(hof + 0) * IN_F),
                    LPTR(&smem[reg * 1024 + 0 + wave * 64]), 16, 0, 0);
                __builtin_amdgcn_global_load_lds(GPTR(src + (size_t)(hof + 64) * IN_F),
                    LPTR(&smem[reg * 1024 + 512 + wave * 64]), 16, 0, 0);
            }
            if (p == 0) {
                // drains exactly kt's 4 halves; keeps the fresh half in flight
                asm volatile("s_waitcnt vmcnt(2)" ::: "memory");
                __builtin_amdgcn_sched_barrier(0);
                __builtin_amdgcn_s_barrier();     // staging now visible to all
            }
            const int kg = ((p >> 1) * 4 + q) ^ xr;
            v8bf a[4], b[4];
            #pragma unroll
            for (int i = 0; i < 4; ++i)
                a[i] = *reinterpret_cast<const v8bf*>(
                    &smem[bufb * 4096 + aRow + ((p & 1) * 4 + i) * 128 + kg]);
            #pragma unroll
            for (int j = 0; j < 4; ++j)
                b[j] = *reinterpret_cast<const v8bf*>(
                    &smem[bufb * 4096 + bRow + j * 128 + kg]);
            __builtin_amdgcn_s_setprio(1);
            #pragma unroll
            for (int i = 0; i < 4; ++i)
                #pragma unroll
                for (int j = 0; j < 4; ++j)
                    acc[(p & 1) * 4 + i][j] = __builtin_amdgcn_mfma_f32_16x16x32_bf16(
                        a[i], b[j], acc[(p & 1) * 4 + i][j], 0, 0, 0);
            __builtin_amdgcn_s_setprio(0);
            __builtin_amdgcn_s_barrier();
        }
    }

    // epilogue K-tile (kt = 63, bufb = 1): no staging, full drain once.
    {
        const int bufb = 1;
        #pragma unroll
        for (int p = 0; p < 4; ++p) {
            if (p == 0) {
                asm volatile("s_waitcnt vmcnt(0)" ::: "memory");
                __builtin_amdgcn_sched_barrier(0);
                __builtin_amdgcn_s_barrier();
            }
            const int kg = ((p >> 1) * 4 + q) ^ xr;
            v8bf a[4], b[4];
            #pragma unroll
            for (int i = 0; i < 4; ++i)
                a[i] = *reinterpret_cast<const v8bf*>(
                    &smem[bufb * 4096 + aRow + ((p & 1) * 4 + i) * 128 + kg]);
            #pragma unroll
            for (int j = 0; j < 4; ++j)
                b[j] = *reinterpret_cast<const v8bf*>(
                    &smem[bufb * 4096 + bRow + j * 128 + kg]);
            __builtin_amdgcn_s_setprio(1);
            #pragma unroll
            for (int i = 0; i < 4; ++i)
                #pragma unroll
                for (int j = 0; j < 4; ++j)
                    acc[(p & 1) * 4 + i][j] = __builtin_amdgcn_mfma_f32_16x16x32_bf16(
                        a[i], b[j], acc[(p & 1) * 4 + i][j], 0, 0, 0);
            __builtin_amdgcn_s_setprio(0);
            __builtin_amdgcn_s_barrier();
        }
    }

    // epilogue: C/D layout (m89/m91): col = lane&15, row = q*4 + reg
    float bf4[4];
    #pragma unroll
    for (int nf = 0; nf < 4; ++nf)
        bf4[nf] = bias[bn * 256 + wn * 64 + nf * 16 + ml];

    #pragma unroll
    for (int mf = 0; mf < 8; ++mf) {
        const int row0 = bm * 256 + wm * 128 + mf * 16 + q * 4;
        #pragma unroll
        for (int nf = 0; nf < 4; ++nf) {
            const int col = bn * 256 + wn * 64 + nf * 16 + ml;
            float* yp = Y + (size_t)row0 * OUT_F + col;
            #pragma unroll
            for (int r = 0; r < 4; ++r)
                yp[(size_t)r * OUT_F] = acc[mf][nf][r] + bf4[nf];
        }
    }
}

// ---------------------------------------------------------------------------
// Fallback (ws too small for 96 MiB): fp32 LDS-staged gather.
// ---------------------------------------------------------------------------
__global__ __launch_bounds__(256) void fallback_kernel(
    const float* __restrict__ x,
    const float* __restrict__ values,
    const int* __restrict__ col_idx,
    const float* __restrict__ bias,
    float* __restrict__ y)
{
    __shared__ float xrow[IN_F];
    const int b = blockIdx.y;
    const int t = threadIdx.x;
    for (int i = t; i < IN_F; i += 256)
        xrow[i] = x[(size_t)b * IN_F + i];
    __syncthreads();
    const int o    = blockIdx.x * 256 + t;
    const int base = o * CAP;
    float acc = bias[o];
    for (int k = 0; k < CAP; ++k)
        acc += values[base + k] * xrow[col_idx[base + k]];
    y[(size_t)b * OUT_F + o] = acc;
}

extern "C" void kernel_launch(void* const* d_in, const int* in_sizes, int n_in,
                              void* d_out, int out_size, void* d_ws, size_t ws_size,
                              hipStream_t stream)
{
    const float* x      = (const float*)d_in[0];
    const float* values = (const float*)d_in[1];
    const int*   colidx = (const int*)d_in[2];
    const float* bias   = (const float*)d_in[3];
    float*       y      = (float*)d_out;

    const size_t w_bytes  = (size_t)OUT_F * IN_F * sizeof(__hip_bfloat16);  // 32 MiB
    const size_t xb_bytes = (size_t)BATCH * IN_F * sizeof(__hip_bfloat16);  // 64 MiB
    if (ws_size >= w_bytes + xb_bytes) {
        __hip_bfloat16* W  = (__hip_bfloat16*)d_ws;
        __hip_bfloat16* Xb = (__hip_bfloat16*)((char*)d_ws + w_bytes);

        convert_kernel<<<(BATCH * IN_F / 4) / 8192, 256, 0, stream>>>(
            (const float4*)x, (v4bf*)Xb);
        densify_kernel<<<OUT_F / 2, 256, 0, stream>>>(values, colidx, W);

        dim3 grid(OUT_F / 256, BATCH / 256);
        gemm_bias_kernel<<<grid, 512, 0, stream>>>(Xb, W, bias, y);
    } else {
        dim3 grid(OUT_F / 256, BATCH);
        fallback_kernel<<<grid, 256, 0, stream>>>(x, values, colidx, bias, y);
    }
}